// Round 5
// baseline (877.003 us; speedup 1.0000x reference)
//
#include <hip/hip_runtime.h>
#include <hip/hip_bf16.h>
#include <hip/hip_fp16.h>
#include <stdint.h>

#define T_STEPS 256
#define BATCH 512

typedef _Float16 f16x8 __attribute__((ext_vector_type(8)));
typedef _Float16 h2_t  __attribute__((ext_vector_type(2)));
typedef float    f32x4 __attribute__((ext_vector_type(4)));

__device__ __forceinline__ float fdot2(uint32_t w, uint32_t c, float acc) {
#if __has_builtin(__builtin_amdgcn_fdot2)
    h2_t a, b;
    __builtin_memcpy(&a, &w, 4);
    __builtin_memcpy(&b, &c, 4);
    return __builtin_amdgcn_fdot2(a, b, acc, false);
#else
    union { uint32_t u; _Float16 h[2]; } A, B;
    A.u = w; B.u = c;
    return acc + (float)A.h[0]*(float)B.h[0] + (float)A.h[1]*(float)B.h[1];
#endif
}

__device__ __forceinline__ float sigmoidf_(float x) {
    return 1.f / (1.f + __expf(-x));
}
__device__ __forceinline__ float tanhf_(float x) {
    float ax = fabsf(x);
    float e = __expf(-2.f * ax);
    float r = (1.f - e) / (1.f + e);
    return copysignf(r, x);
}

// ---------------- prep: concat QCNN weights into one buffer ----------------
__global__ void concat_qw(const float* __restrict__ fm_w, const float* __restrict__ fm_b,
                          const float* __restrict__ c1_w, const float* __restrict__ c1_b,
                          const float* __restrict__ p1_w, const float* __restrict__ p1_b,
                          const float* __restrict__ c2_w, const float* __restrict__ c2_b,
                          const float* __restrict__ p2_w, const float* __restrict__ p2_b,
                          const float* __restrict__ c3_w, const float* __restrict__ c3_b,
                          float* __restrict__ qw) {
    for (int k = threadIdx.x; k < 780; k += 256) {
        float v;
        if      (k < 128) v = fm_w[k];
        else if (k < 144) v = fm_b[k-128];
        else if (k < 400) v = c1_w[k-144];
        else if (k < 416) v = c1_b[k-400];
        else if (k < 608) v = p1_w[k-416];
        else if (k < 620) v = p1_b[k-608];
        else if (k < 716) v = c2_w[k-620];
        else if (k < 724) v = c2_b[k-716];
        else if (k < 756) v = p2_w[k-724];
        else if (k < 760) v = p2_b[k-756];
        else if (k < 776) v = c3_w[k-760];
        else              v = c3_b[k-776];
        qw[k] = v;
    }
}

// ---------------- prep: pack LSTM h-weights as MFMA B-fragments (f16) ----------------
// B-frag for mfma_f32_16x16x32_f16: lane l holds col l&15, k = (l>>4)*8 + e.
// k-element-order errors cancel between A and B (we pack B and read A with the
// same mapping). bfragsG[((n*8+q)*64+l)]: n = N-tile (16 cols), q = K-tile.
__global__ void pack_bfrag(const float* __restrict__ f_w, const float* __restrict__ i_w,
                           const float* __restrict__ u_w, const float* __restrict__ o_w,
                           uint4* __restrict__ bfragsG) {
    int idx = blockIdx.x * 256 + threadIdx.x;      // 0..32767
    int l = idx & 63, q = (idx >> 6) & 7, n = idx >> 9;
    int col = n * 16 + (l & 15);
    int g = col >> 8, j = col & 255;
    const float* W = (g == 0) ? f_w : (g == 1) ? i_w : (g == 2) ? u_w : o_w;
    union { uint4 u; _Float16 h[8]; } P;
#pragma unroll
    for (int e = 0; e < 8; ++e) {
        int k = q * 32 + ((l >> 4) * 8) + e;       // 0..255 (h part only)
        P.h[e] = (_Float16)W[j * 260 + 4 + k];
    }
    bfragsG[idx] = P.u;
}

// ---------------- prep: pack x-part weights xwG[g][k][j] f16 ----------------
__global__ void pack_xw(const float* __restrict__ f_w, const float* __restrict__ i_w,
                        const float* __restrict__ u_w, const float* __restrict__ o_w,
                        _Float16* __restrict__ xwG) {
    int t = blockIdx.x * 256 + threadIdx.x;        // 0..4095
    int g = t >> 10, k = (t >> 8) & 3, j = t & 255;
    const float* W = (g == 0) ? f_w : (g == 1) ? i_w : (g == 2) ? u_w : o_w;
    xwG[t] = (_Float16)W[j * 260 + k];
}

// ---------------- QCNN feature extractor: one thread per (t,b) row ----------------
__global__ void qcnn_kernel(const float* __restrict__ in, const float* __restrict__ qw,
                            _Float16* __restrict__ feats) {
    int r = blockIdx.x * 256 + threadIdx.x;   // 0..131071
    const float* x = in + (size_t)r * 8;
    float v0[8];
#pragma unroll
    for (int i = 0; i < 8; ++i) v0[i] = x[i];
    float v1[16];
#pragma unroll
    for (int o = 0; o < 16; ++o) {
        float s = qw[128 + o];
#pragma unroll
        for (int i = 0; i < 8; ++i) s += qw[o*8 + i] * v0[i];
        v1[o] = tanhf_(s);
    }
    float v2[16];
#pragma unroll
    for (int o = 0; o < 16; ++o) {
        float s = qw[400 + o];
#pragma unroll
        for (int i = 0; i < 16; ++i) s += qw[144 + o*16 + i] * v1[i];
        v2[o] = tanhf_(s);
    }
    float v3[12];
#pragma unroll
    for (int o = 0; o < 12; ++o) {
        float s = qw[608 + o];
#pragma unroll
        for (int i = 0; i < 16; ++i) s += qw[416 + o*16 + i] * v2[i];
        v3[o] = tanhf_(s);
    }
    float v4[8];
#pragma unroll
    for (int o = 0; o < 8; ++o) {
        float s = qw[716 + o];
#pragma unroll
        for (int i = 0; i < 12; ++i) s += qw[620 + o*12 + i] * v3[i];
        v4[o] = tanhf_(s);
    }
    float v5[4];
#pragma unroll
    for (int o = 0; o < 4; ++o) {
        float s = qw[756 + o];
#pragma unroll
        for (int i = 0; i < 8; ++i) s += qw[724 + o*8 + i] * v4[i];
        v5[o] = tanhf_(s);
    }
    union { uint32_t u[2]; _Float16 h[4]; } P;
#pragma unroll
    for (int o = 0; o < 4; ++o) {
        float s = qw[776 + o];
#pragma unroll
        for (int i = 0; i < 4; ++i) s += qw[760 + o*4 + i] * v5[i];
        P.h[o] = (_Float16)tanhf_(s);
    }
    *reinterpret_cast<uint2*>(feats + (size_t)r * 4) = make_uint2(P.u[0], P.u[1]);
}

// ---------------- persistent MFMA LSTM: 256 blocks x 256 threads, 2 samples/block ----
// 4 waves, 1 wave/SIMD. Wave w owns output dims j in [w*64, w*64+64): N-tiles
// n(g,d) = g*16 + w*4 + d (g = gate 0..3 = f,i,u,o; d = 0..3) -> all 4 gates of
// any j live in the SAME wave. K-tiles q=0..5 register-resident (96 frags),
// q=6,7 streamed from LDS. Per step: MFMA (128, ~2170 cy pipe floor/SIMD) ->
// per-wave strip extraction + wave-local lgkmcnt (NO block barrier) -> all-lane
// epilogue (2 (s,j) updates/lane; bias/xw/head weights preloaded in regs) ->
// ONE __syncthreads per step. C/D layout (HW-verified m89): col = lane&15,
// row = (lane>>4)*4 + reg; rows 0,1 = samples, rows 2-15 garbage (harmless:
// each C row depends only on its A row).
__global__ __launch_bounds__(256, 1)
void lstm_kernel(const uint4* __restrict__ bfragsG, const _Float16* __restrict__ xwG,
                 const _Float16* __restrict__ feats,
                 const float* __restrict__ f_b, const float* __restrict__ i_b,
                 const float* __restrict__ u_b, const float* __restrict__ o_b,
                 const float* __restrict__ head_w, const float* __restrict__ head_bp,
                 float* __restrict__ out) {
    __shared__ uint4     bldsL[2][64][64];      // 131072 B : B-frags q=6,7
    __shared__ float     stripL[4][4][64][2];   //   8192 B : [wave][g][jl][sample]
    __shared__ _Float16  combL[2][2][256];      //   2048 B : [buf][sample][k] h state
    __shared__ float     redL[2][2][4];         //     64 B : [buf][sample][wave]

    const int tid = threadIdx.x;
    const int w   = tid >> 6;          // wave 0..3
    const int l   = tid & 63;          // lane
    const int s0  = blockIdx.x * 2;
    const int j   = w * 64 + l;        // this lane's epilogue output dim

    // ---- init LDS ----
    for (int i = tid; i < 8192; i += 256) {
        int n = i >> 7, qq = (i >> 6) & 1, ll = i & 63;
        bldsL[qq][n][ll] = bfragsG[(n * 8 + 6 + qq) * 64 + ll];
    }
    reinterpret_cast<uint32_t*>(&combL[0][0][0])[tid] = 0u;   // zero h_0 (buf 0)

    // ---- per-lane register preloads (step-invariant) ----
    f16x8 Breg[16][6];
#pragma unroll
    for (int m = 0; m < 16; ++m) {
        const int n = (m >> 2) * 16 + w * 4 + (m & 3);
#pragma unroll
        for (int q = 0; q < 6; ++q)
            Breg[m][q] = *reinterpret_cast<const f16x8*>(bfragsG + (n * 8 + q) * 64 + l);
    }
    float bias_[4] = { f_b[j], i_b[j], u_b[j], o_b[j] };
    const float hwj = head_w[j];
    const float hb  = head_bp[0];
    uint32_t xw01[4], xw23[4];                 // f16x2 pairs of x-weights per gate
#pragma unroll
    for (int g = 0; g < 4; ++g) {
        union { uint32_t u; _Float16 h[2]; } P;
        P.h[0] = xwG[g*1024 +       j]; P.h[1] = xwG[g*1024 + 256 + j];
        xw01[g] = P.u;
        P.h[0] = xwG[g*1024 + 512 + j]; P.h[1] = xwG[g*1024 + 768 + j];
        xw23[g] = P.u;
    }
    // x_0 (broadcast 8B loads; all lanes same addr -> L2 broadcast)
    uint2 xr0 = *reinterpret_cast<const uint2*>(feats + ((size_t)0 * BATCH + s0    ) * 4);
    uint2 xr1 = *reinterpret_cast<const uint2*>(feats + ((size_t)0 * BATCH + s0 + 1) * 4);

    __syncthreads();

    float c0 = 0.f, c1 = 0.f;          // c-state for (j, sample 0/1)

#pragma unroll 1
    for (int t = 0; t < T_STEPS; ++t) {
        // prefetch x_{t+1}; first use is next iteration's epilogue (~1 step of cover)
        uint2 xn0 = xr0, xn1 = xr1;
        if (t + 1 < T_STEPS) {
            xn0 = *reinterpret_cast<const uint2*>(feats + ((size_t)(t+1) * BATCH + s0    ) * 4);
            xn1 = *reinterpret_cast<const uint2*>(feats + ((size_t)(t+1) * BATCH + s0 + 1) * 4);
        }

        // ---- MFMA phase: C[2 x 1024] = comb[2 x 256] . W^T, A-frags 1-ahead ----
        const _Float16* abase = &combL[t & 1][l & 1][(l >> 4) * 8];
        f32x4 C[16] = {};
        f16x8 a_cur = *reinterpret_cast<const f16x8*>(abase);
#pragma unroll
        for (int q = 0; q < 8; ++q) {
            f16x8 a_nxt;
            if (q < 7) a_nxt = *reinterpret_cast<const f16x8*>(abase + (q + 1) * 32);
#pragma unroll
            for (int m = 0; m < 16; ++m) {
                f16x8 b;
                if (q < 6) b = Breg[m][q];
                else {
                    const int n = (m >> 2) * 16 + w * 4 + (m & 3);
                    b = *reinterpret_cast<const f16x8*>(&bldsL[q - 6][n][l]);
                }
                C[m] = __builtin_amdgcn_mfma_f32_16x16x32_f16(a_cur, b, C[m], 0, 0, 0);
            }
            a_cur = a_nxt;
        }

        // ---- wave-local extraction: rows 0,1 of each tile -> this wave's strip ----
        if (l < 16) {
#pragma unroll
            for (int m = 0; m < 16; ++m)
                *reinterpret_cast<float2*>(&stripL[w][m >> 2][(m & 3) * 16 + l][0]) =
                    make_float2(C[m][0], C[m][1]);
        }
        // same-wave producer/consumer: drain LDS writes, keep compiler from reordering
        asm volatile("s_waitcnt lgkmcnt(0)" ::: "memory");
        __builtin_amdgcn_wave_barrier();

        // ---- all-lane epilogue: lane handles (j, s=0) and (j, s=1) ----
        float pre0[4], pre1[4];
#pragma unroll
        for (int g = 0; g < 4; ++g) {
            float2 gv = *reinterpret_cast<const float2*>(&stripL[w][g][l][0]);
            pre0[g] = fdot2(xw01[g], xr0.x, fdot2(xw23[g], xr0.y, gv.x + bias_[g]));
            pre1[g] = fdot2(xw01[g], xr1.x, fdot2(xw23[g], xr1.y, gv.y + bias_[g]));
        }
        const float fg0 = sigmoidf_(pre0[0]), fg1 = sigmoidf_(pre1[0]);
        const float ig0 = sigmoidf_(pre0[1]), ig1 = sigmoidf_(pre1[1]);
        const float ug0 = tanhf_(pre0[2]),    ug1 = tanhf_(pre1[2]);
        const float og0 = sigmoidf_(pre0[3]), og1 = sigmoidf_(pre1[3]);
        c0 = fg0 * c0 + ig0 * ug0;
        c1 = fg1 * c1 + ig1 * ug1;
        const float h0 = og0 * tanhf_(c0);
        const float h1 = og1 * tanhf_(c1);

        _Float16* nb = &combL[(t + 1) & 1][0][0];
        nb[j]       = (_Float16)h0;
        nb[256 + j] = (_Float16)h1;

        // head partials: full-wave reduce (64 j-dims per wave)
        float p0 = h0 * hwj, p1 = h1 * hwj;
#pragma unroll
        for (int off = 32; off; off >>= 1) {
            p0 += __shfl_down(p0, off);
            p1 += __shfl_down(p1, off);
        }
        if (l == 0) { redL[t & 1][0][w] = p0; redL[t & 1][1][w] = p1; }

        xr0 = xn0; xr1 = xn1;
        __syncthreads();                       // the ONE barrier per step

        if (tid < 2)
            out[(size_t)t * BATCH + s0 + tid] =
                (redL[t & 1][tid][0] + redL[t & 1][tid][1]) +
                (redL[t & 1][tid][2] + redL[t & 1][tid][3]) + hb;
    }
}

extern "C" void kernel_launch(void* const* d_in, const int* in_sizes, int n_in,
                              void* d_out, int out_size, void* d_ws, size_t ws_size,
                              hipStream_t stream) {
    const float* inputs = (const float*)d_in[0];
    const float* fm_w = (const float*)d_in[1];  const float* fm_b = (const float*)d_in[2];
    const float* c1_w = (const float*)d_in[3];  const float* c1_b = (const float*)d_in[4];
    const float* p1_w = (const float*)d_in[5];  const float* p1_b = (const float*)d_in[6];
    const float* c2_w = (const float*)d_in[7];  const float* c2_b = (const float*)d_in[8];
    const float* p2_w = (const float*)d_in[9];  const float* p2_b = (const float*)d_in[10];
    const float* c3_w = (const float*)d_in[11]; const float* c3_b = (const float*)d_in[12];
    const float* f_w  = (const float*)d_in[13]; const float* f_b  = (const float*)d_in[14];
    const float* i_w  = (const float*)d_in[15]; const float* i_b  = (const float*)d_in[16];
    const float* u_w  = (const float*)d_in[17]; const float* u_b  = (const float*)d_in[18];
    const float* o_w  = (const float*)d_in[19]; const float* o_b  = (const float*)d_in[20];
    const float* head_w = (const float*)d_in[21];
    const float* head_b = (const float*)d_in[22];

    // workspace layout (16B aligned)
    uint4*     bfragsG = (uint4*)d_ws;                                // 524288 B
    _Float16*  xwG     = (_Float16*)((char*)d_ws + 524288);           //   8192 B
    _Float16*  feats   = (_Float16*)((char*)d_ws + 532480);           // 1048576 B
    float*     qw      = (float*)((char*)d_ws + 1581056);             //   3120 B

    hipLaunchKernelGGL(concat_qw, dim3(1), dim3(256), 0, stream,
                       fm_w, fm_b, c1_w, c1_b, p1_w, p1_b, c2_w, c2_b,
                       p2_w, p2_b, c3_w, c3_b, qw);
    hipLaunchKernelGGL(pack_bfrag, dim3(128), dim3(256), 0, stream,
                       f_w, i_w, u_w, o_w, bfragsG);
    hipLaunchKernelGGL(pack_xw, dim3(16), dim3(256), 0, stream,
                       f_w, i_w, u_w, o_w, xwG);
    hipLaunchKernelGGL(qcnn_kernel, dim3(512), dim3(256), 0, stream,
                       inputs, qw, feats);
    hipLaunchKernelGGL(lstm_kernel, dim3(256), dim3(256), 0, stream,
                       bfragsG, xwG, feats,
                       f_b, i_b, u_b, o_b, head_w, head_b, (float*)d_out);
}

// Round 6
// 705.945 us; speedup vs baseline: 1.2423x; 1.2423x over previous
//
#include <hip/hip_runtime.h>
#include <hip/hip_bf16.h>
#include <hip/hip_fp16.h>
#include <stdint.h>

#define T_STEPS 256
#define BATCH 512

typedef _Float16 f16x8 __attribute__((ext_vector_type(8)));
typedef _Float16 h2_t  __attribute__((ext_vector_type(2)));
typedef float    f32x4 __attribute__((ext_vector_type(4)));

__device__ __forceinline__ float fdot2(uint32_t w, uint32_t c, float acc) {
#if __has_builtin(__builtin_amdgcn_fdot2)
    h2_t a, b;
    __builtin_memcpy(&a, &w, 4);
    __builtin_memcpy(&b, &c, 4);
    return __builtin_amdgcn_fdot2(a, b, acc, false);
#else
    union { uint32_t u; _Float16 h[2]; } A, B;
    A.u = w; B.u = c;
    return acc + (float)A.h[0]*(float)B.h[0] + (float)A.h[1]*(float)B.h[1];
#endif
}

__device__ __forceinline__ float sigmoidf_(float x) {
    return 1.f / (1.f + __expf(-x));
}
__device__ __forceinline__ float tanhf_(float x) {
    float ax = fabsf(x);
    float e = __expf(-2.f * ax);
    float r = (1.f - e) / (1.f + e);
    return copysignf(r, x);
}

// resident-B MFMA: B pinned in AGPR via "a" constraint (not rematerializable)
#define MFMA_AG(c, aa, bb) \
    asm volatile("v_mfma_f32_16x16x32_f16 %0, %1, %2, %0" : "+v"(c) : "v"(aa), "a"(bb))
// LDS-streamed B in VGPR
#define MFMA_VG(c, aa, bb) \
    asm volatile("v_mfma_f32_16x16x32_f16 %0, %1, %2, %0" : "+v"(c) : "v"(aa), "v"(bb))

// ---------------- prep: concat QCNN weights into one buffer ----------------
__global__ void concat_qw(const float* __restrict__ fm_w, const float* __restrict__ fm_b,
                          const float* __restrict__ c1_w, const float* __restrict__ c1_b,
                          const float* __restrict__ p1_w, const float* __restrict__ p1_b,
                          const float* __restrict__ c2_w, const float* __restrict__ c2_b,
                          const float* __restrict__ p2_w, const float* __restrict__ p2_b,
                          const float* __restrict__ c3_w, const float* __restrict__ c3_b,
                          float* __restrict__ qw) {
    for (int k = threadIdx.x; k < 780; k += 256) {
        float v;
        if      (k < 128) v = fm_w[k];
        else if (k < 144) v = fm_b[k-128];
        else if (k < 400) v = c1_w[k-144];
        else if (k < 416) v = c1_b[k-400];
        else if (k < 608) v = p1_w[k-416];
        else if (k < 620) v = p1_b[k-608];
        else if (k < 716) v = c2_w[k-620];
        else if (k < 724) v = c2_b[k-716];
        else if (k < 756) v = p2_w[k-724];
        else if (k < 760) v = p2_b[k-756];
        else if (k < 776) v = c3_w[k-760];
        else              v = c3_b[k-776];
        qw[k] = v;
    }
}

// ---------------- prep: pack LSTM h-weights as MFMA B-fragments (f16) ----------------
// B-frag for mfma_f32_16x16x32_f16: lane l holds col l&15, k = (l>>4)*8 + e.
// k-element-order errors cancel between A and B (we pack B and read A with the
// same mapping). bfragsG[((n*8+q)*64+l)]: n = N-tile (16 cols), q = K-tile.
__global__ void pack_bfrag(const float* __restrict__ f_w, const float* __restrict__ i_w,
                           const float* __restrict__ u_w, const float* __restrict__ o_w,
                           uint4* __restrict__ bfragsG) {
    int idx = blockIdx.x * 256 + threadIdx.x;      // 0..32767
    int l = idx & 63, q = (idx >> 6) & 7, n = idx >> 9;
    int col = n * 16 + (l & 15);
    int g = col >> 8, j = col & 255;
    const float* W = (g == 0) ? f_w : (g == 1) ? i_w : (g == 2) ? u_w : o_w;
    union { uint4 u; _Float16 h[8]; } P;
#pragma unroll
    for (int e = 0; e < 8; ++e) {
        int k = q * 32 + ((l >> 4) * 8) + e;       // 0..255 (h part only)
        P.h[e] = (_Float16)W[j * 260 + 4 + k];
    }
    bfragsG[idx] = P.u;
}

// ---------------- prep: pack x-part weights xwG[g][k][j] f16 ----------------
__global__ void pack_xw(const float* __restrict__ f_w, const float* __restrict__ i_w,
                        const float* __restrict__ u_w, const float* __restrict__ o_w,
                        _Float16* __restrict__ xwG) {
    int t = blockIdx.x * 256 + threadIdx.x;        // 0..4095
    int g = t >> 10, k = (t >> 8) & 3, j = t & 255;
    const float* W = (g == 0) ? f_w : (g == 1) ? i_w : (g == 2) ? u_w : o_w;
    xwG[t] = (_Float16)W[j * 260 + k];
}

// ---------------- QCNN feature extractor: one thread per (t,b) row ----------------
__global__ void qcnn_kernel(const float* __restrict__ in, const float* __restrict__ qw,
                            _Float16* __restrict__ feats) {
    int r = blockIdx.x * 256 + threadIdx.x;   // 0..131071
    const float* x = in + (size_t)r * 8;
    float v0[8];
#pragma unroll
    for (int i = 0; i < 8; ++i) v0[i] = x[i];
    float v1[16];
#pragma unroll
    for (int o = 0; o < 16; ++o) {
        float s = qw[128 + o];
#pragma unroll
        for (int i = 0; i < 8; ++i) s += qw[o*8 + i] * v0[i];
        v1[o] = tanhf_(s);
    }
    float v2[16];
#pragma unroll
    for (int o = 0; o < 16; ++o) {
        float s = qw[400 + o];
#pragma unroll
        for (int i = 0; i < 16; ++i) s += qw[144 + o*16 + i] * v1[i];
        v2[o] = tanhf_(s);
    }
    float v3[12];
#pragma unroll
    for (int o = 0; o < 12; ++o) {
        float s = qw[608 + o];
#pragma unroll
        for (int i = 0; i < 16; ++i) s += qw[416 + o*16 + i] * v2[i];
        v3[o] = tanhf_(s);
    }
    float v4[8];
#pragma unroll
    for (int o = 0; o < 8; ++o) {
        float s = qw[716 + o];
#pragma unroll
        for (int i = 0; i < 12; ++i) s += qw[620 + o*12 + i] * v3[i];
        v4[o] = tanhf_(s);
    }
    float v5[4];
#pragma unroll
    for (int o = 0; o < 4; ++o) {
        float s = qw[756 + o];
#pragma unroll
        for (int i = 0; i < 8; ++i) s += qw[724 + o*8 + i] * v4[i];
        v5[o] = tanhf_(s);
    }
    union { uint32_t u[2]; _Float16 h[4]; } P;
#pragma unroll
    for (int o = 0; o < 4; ++o) {
        float s = qw[776 + o];
#pragma unroll
        for (int i = 0; i < 4; ++i) s += qw[760 + o*4 + i] * v5[i];
        P.h[o] = (_Float16)tanhf_(s);
    }
    *reinterpret_cast<uint2*>(feats + (size_t)r * 4) = make_uint2(P.u[0], P.u[1]);
}

// ---------------- persistent MFMA LSTM: 256 blocks x 256 threads, 2 samples/block ----
// Register-budget analysis (round 5 failure): Breg 96 frags (384) + C[16] (64)
// + A (32) + misc (~80) = 560 > 512 unified regs -> compiler silently
// rematerialized B from global each step = 28 TB/s of L2 reads (the measured
// ceiling). Fix: (a) only 92 frags resident, pinned in AGPR via inline-asm "a"
// constraints (not rematerializable); (b) m-outer/q-inner in 4-tile gate
// blocks so only C[4] (16 VGPR) is live. VGPR ~130 + AGPR 368 = ~500 <= 512.
// LDS B: q=6,7 all 64 tiles (128 KB) + q=5 tiles 48..63 (16 KB).
__global__ __launch_bounds__(256, 1)
void lstm_kernel(const uint4* __restrict__ bfragsG, const _Float16* __restrict__ xwG,
                 const _Float16* __restrict__ feats,
                 const float* __restrict__ f_b, const float* __restrict__ i_b,
                 const float* __restrict__ u_b, const float* __restrict__ o_b,
                 const float* __restrict__ head_w, const float* __restrict__ head_bp,
                 float* __restrict__ out) {
    __shared__ uint4     bldsQ67[2][64][64];         // 131072 B : B q=6,7
    __shared__ uint4     bldsQ5o[16][64];            //  16384 B : B q=5, tiles 48..63
    __shared__ float     stripL[4][4][64][2];        //   8192 B : [wave][g][jl][sample]
    __shared__ __align__(16) _Float16 combL[2][2][256]; // 2048 B : [buf][sample][k]
    __shared__ float     redL[2][2][4];              //     64 B

    const int tid = threadIdx.x;
    const int w   = tid >> 6;          // wave 0..3
    const int l   = tid & 63;          // lane
    const int s0  = blockIdx.x * 2;
    const int j   = w * 64 + l;        // epilogue output dim

    // ---- init LDS ----
    for (int i = tid; i < 8192; i += 256) {
        int n = i >> 7, qq = (i >> 6) & 1, ll = i & 63;
        bldsQ67[qq][n][ll] = bfragsG[(n * 8 + 6 + qq) * 64 + ll];
    }
    for (int i = tid; i < 1024; i += 256) {
        int nn = i >> 6, ll = i & 63;
        bldsQ5o[nn][ll] = bfragsG[((48 + nn) * 8 + 5) * 64 + ll];
    }
    reinterpret_cast<uint32_t*>(&combL[0][0][0])[tid] = 0u;   // zero h_0 (buf 0)

    // ---- resident B fragments -> AGPR (pinned). [12..15][5] never used. ----
    f16x8 Breg[16][6];
#pragma unroll
    for (int m = 0; m < 16; ++m) {
        const int n = (m >> 2) * 16 + w * 4 + (m & 3);
#pragma unroll
        for (int q = 0; q < 6; ++q) {
            if (m >= 12 && q == 5) continue;        // LDS-streamed instead
            Breg[m][q] = *reinterpret_cast<const f16x8*>(bfragsG + (n * 8 + q) * 64 + l);
            asm volatile("" : "+a"(Breg[m][q]));    // pin live range to AGPR
        }
    }

    float bias_[4] = { f_b[j], i_b[j], u_b[j], o_b[j] };
    const float hwj = head_w[j];
    const float hb  = head_bp[0];
    uint32_t xw01[4], xw23[4];
#pragma unroll
    for (int g = 0; g < 4; ++g) {
        union { uint32_t u; _Float16 h[2]; } P;
        P.h[0] = xwG[g*1024 +       j]; P.h[1] = xwG[g*1024 + 256 + j];
        xw01[g] = P.u;
        P.h[0] = xwG[g*1024 + 512 + j]; P.h[1] = xwG[g*1024 + 768 + j];
        xw23[g] = P.u;
    }
    uint2 xr0 = *reinterpret_cast<const uint2*>(feats + ((size_t)0 * BATCH + s0    ) * 4);
    uint2 xr1 = *reinterpret_cast<const uint2*>(feats + ((size_t)0 * BATCH + s0 + 1) * 4);

    __syncthreads();

    float cs0 = 0.f, cs1 = 0.f;        // c-state for (j, sample 0/1)

#pragma unroll 1
    for (int t = 0; t < T_STEPS; ++t) {
        uint2 xn0 = xr0, xn1 = xr1;
        if (t + 1 < T_STEPS) {
            xn0 = *reinterpret_cast<const uint2*>(feats + ((size_t)(t+1) * BATCH + s0    ) * 4);
            xn1 = *reinterpret_cast<const uint2*>(feats + ((size_t)(t+1) * BATCH + s0 + 1) * 4);
        }

        // ---- A fragments for this step (8 x ds_read_b128) ----
        const _Float16* abase = &combL[t & 1][l & 1][(l >> 4) * 8];
        f16x8 A_[8];
#pragma unroll
        for (int q = 0; q < 8; ++q)
            A_[q] = *reinterpret_cast<const f16x8*>(abase + q * 32);

        // ---- 4 gate blocks: tiles m = 4b..4b+3, C[4] live per block ----
#pragma unroll
        for (int b = 0; b < 4; ++b) {
            // LDS-sourced B frags for this block (scheduler hoists the loads)
            f16x8 t6[4], t7[4], t5[4];
#pragma unroll
            for (int d = 0; d < 4; ++d) {
                const int n = b * 16 + w * 4 + d;
                t6[d] = *reinterpret_cast<const f16x8*>(&bldsQ67[0][n][l]);
                t7[d] = *reinterpret_cast<const f16x8*>(&bldsQ67[1][n][l]);
            }
            if (b == 3) {
#pragma unroll
                for (int d = 0; d < 4; ++d)
                    t5[d] = *reinterpret_cast<const f16x8*>(&bldsQ5o[w * 4 + d][l]);
            }

            f32x4 c0 = {0.f,0.f,0.f,0.f}, c1 = {0.f,0.f,0.f,0.f};
            f32x4 c2 = {0.f,0.f,0.f,0.f}, c3 = {0.f,0.f,0.f,0.f};
            asm volatile("s_nop 1" : "+v"(c0), "+v"(c1), "+v"(c2), "+v"(c3));

            // LDS q's first (loads just issued, consumed here; temps freed early)
            MFMA_VG(c0, A_[6], t6[0]); MFMA_VG(c1, A_[6], t6[1]);
            MFMA_VG(c2, A_[6], t6[2]); MFMA_VG(c3, A_[6], t6[3]);
            MFMA_VG(c0, A_[7], t7[0]); MFMA_VG(c1, A_[7], t7[1]);
            MFMA_VG(c2, A_[7], t7[2]); MFMA_VG(c3, A_[7], t7[3]);
            if (b == 3) {
                MFMA_VG(c0, A_[5], t5[0]); MFMA_VG(c1, A_[5], t5[1]);
                MFMA_VG(c2, A_[5], t5[2]); MFMA_VG(c3, A_[5], t5[3]);
            }
            // resident q's from AGPR
#pragma unroll
            for (int q = 0; q < 5; ++q) {
                MFMA_AG(c0, A_[q], Breg[4*b+0][q]); MFMA_AG(c1, A_[q], Breg[4*b+1][q]);
                MFMA_AG(c2, A_[q], Breg[4*b+2][q]); MFMA_AG(c3, A_[q], Breg[4*b+3][q]);
            }
            if (b < 3) {
                MFMA_AG(c0, A_[5], Breg[4*b+0][5]); MFMA_AG(c1, A_[5], Breg[4*b+1][5]);
                MFMA_AG(c2, A_[5], Breg[4*b+2][5]); MFMA_AG(c3, A_[5], Breg[4*b+3][5]);
            }

            // MFMA(D in VGPR) -> VALU read hazard spacing
            asm volatile("s_nop 7\n\ts_nop 7" : "+v"(c0), "+v"(c1), "+v"(c2), "+v"(c3));

            if (l < 16) {   // rows 0,1 = samples 0,1 (C layout: col=lane&15, row=reg)
                *reinterpret_cast<float2*>(&stripL[w][b][0*16 + l][0]) = make_float2(c0[0], c0[1]);
                *reinterpret_cast<float2*>(&stripL[w][b][1*16 + l][0]) = make_float2(c1[0], c1[1]);
                *reinterpret_cast<float2*>(&stripL[w][b][2*16 + l][0]) = make_float2(c2[0], c2[1]);
                *reinterpret_cast<float2*>(&stripL[w][b][3*16 + l][0]) = make_float2(c3[0], c3[1]);
            }
        }

        // same-wave producer/consumer: drain LDS writes
        asm volatile("s_waitcnt lgkmcnt(0)" ::: "memory");
        __builtin_amdgcn_wave_barrier();

        // ---- all-lane epilogue: lane handles (j, s=0) and (j, s=1) ----
        float pre0[4], pre1[4];
#pragma unroll
        for (int g = 0; g < 4; ++g) {
            float2 gv = *reinterpret_cast<const float2*>(&stripL[w][g][l][0]);
            pre0[g] = fdot2(xw01[g], xr0.x, fdot2(xw23[g], xr0.y, gv.x + bias_[g]));
            pre1[g] = fdot2(xw01[g], xr1.x, fdot2(xw23[g], xr1.y, gv.y + bias_[g]));
        }
        const float fg0 = sigmoidf_(pre0[0]), fg1 = sigmoidf_(pre1[0]);
        const float ig0 = sigmoidf_(pre0[1]), ig1 = sigmoidf_(pre1[1]);
        const float ug0 = tanhf_(pre0[2]),    ug1 = tanhf_(pre1[2]);
        const float og0 = sigmoidf_(pre0[3]), og1 = sigmoidf_(pre1[3]);
        cs0 = fg0 * cs0 + ig0 * ug0;
        cs1 = fg1 * cs1 + ig1 * ug1;
        const float h0 = og0 * tanhf_(cs0);
        const float h1 = og1 * tanhf_(cs1);

        _Float16* nb = &combL[(t + 1) & 1][0][0];
        nb[j]       = (_Float16)h0;
        nb[256 + j] = (_Float16)h1;

        float p0 = h0 * hwj, p1 = h1 * hwj;
#pragma unroll
        for (int off = 32; off; off >>= 1) {
            p0 += __shfl_down(p0, off);
            p1 += __shfl_down(p1, off);
        }
        if (l == 0) { redL[t & 1][0][w] = p0; redL[t & 1][1][w] = p1; }

        xr0 = xn0; xr1 = xn1;
        __syncthreads();                       // the ONE barrier per step

        if (tid < 2)
            out[(size_t)t * BATCH + s0 + tid] =
                (redL[t & 1][tid][0] + redL[t & 1][tid][1]) +
                (redL[t & 1][tid][2] + redL[t & 1][tid][3]) + hb;
    }
}

extern "C" void kernel_launch(void* const* d_in, const int* in_sizes, int n_in,
                              void* d_out, int out_size, void* d_ws, size_t ws_size,
                              hipStream_t stream) {
    const float* inputs = (const float*)d_in[0];
    const float* fm_w = (const float*)d_in[1];  const float* fm_b = (const float*)d_in[2];
    const float* c1_w = (const float*)d_in[3];  const float* c1_b = (const float*)d_in[4];
    const float* p1_w = (const float*)d_in[5];  const float* p1_b = (const float*)d_in[6];
    const float* c2_w = (const float*)d_in[7];  const float* c2_b = (const float*)d_in[8];
    const float* p2_w = (const float*)d_in[9];  const float* p2_b = (const float*)d_in[10];
    const float* c3_w = (const float*)d_in[11]; const float* c3_b = (const float*)d_in[12];
    const float* f_w  = (const float*)d_in[13]; const float* f_b  = (const float*)d_in[14];
    const float* i_w  = (const float*)d_in[15]; const float* i_b  = (const float*)d_in[16];
    const float* u_w  = (const float*)d_in[17]; const float* u_b  = (const float*)d_in[18];
    const float* o_w  = (const float*)d_in[19]; const float* o_b  = (const float*)d_in[20];
    const float* head_w = (const float*)d_in[21];
    const float* head_b = (const float*)d_in[22];

    // workspace layout (16B aligned)
    uint4*     bfragsG = (uint4*)d_ws;                                // 524288 B
    _Float16*  xwG     = (_Float16*)((char*)d_ws + 524288);           //   8192 B
    _Float16*  feats   = (_Float16*)((char*)d_ws + 532480);           // 1048576 B
    float*     qw      = (float*)((char*)d_ws + 1581056);             //   3120 B

    hipLaunchKernelGGL(concat_qw, dim3(1), dim3(256), 0, stream,
                       fm_w, fm_b, c1_w, c1_b, p1_w, p1_b, c2_w, c2_b,
                       p2_w, p2_b, c3_w, c3_b, qw);
    hipLaunchKernelGGL(pack_bfrag, dim3(128), dim3(256), 0, stream,
                       f_w, i_w, u_w, o_w, bfragsG);
    hipLaunchKernelGGL(pack_xw, dim3(16), dim3(256), 0, stream,
                       f_w, i_w, u_w, o_w, xwG);
    hipLaunchKernelGGL(qcnn_kernel, dim3(512), dim3(256), 0, stream,
                       inputs, qw, feats);
    hipLaunchKernelGGL(lstm_kernel, dim3(256), dim3(256), 0, stream,
                       bfragsG, xwG, feats,
                       f_b, i_b, u_b, o_b, head_w, head_b, (float*)d_out);
}

// Round 7
// 674.800 us; speedup vs baseline: 1.2996x; 1.0462x over previous
//
#include <hip/hip_runtime.h>
#include <hip/hip_bf16.h>
#include <hip/hip_fp16.h>
#include <stdint.h>

#define T_STEPS 256
#define BATCH 512

typedef _Float16 f16x8 __attribute__((ext_vector_type(8)));
typedef _Float16 h2_t  __attribute__((ext_vector_type(2)));
typedef float    f32x4 __attribute__((ext_vector_type(4)));

__device__ __forceinline__ float fdot2(uint32_t w, uint32_t c, float acc) {
#if __has_builtin(__builtin_amdgcn_fdot2)
    h2_t a, b;
    __builtin_memcpy(&a, &w, 4);
    __builtin_memcpy(&b, &c, 4);
    return __builtin_amdgcn_fdot2(a, b, acc, false);
#else
    union { uint32_t u; _Float16 h[2]; } A, B;
    A.u = w; B.u = c;
    return acc + (float)A.h[0]*(float)B.h[0] + (float)A.h[1]*(float)B.h[1];
#endif
}

__device__ __forceinline__ float sigmoidf_(float x) {
    return 1.f / (1.f + __expf(-x));
}
__device__ __forceinline__ float tanhf_(float x) {
    float ax = fabsf(x);
    float e = __expf(-2.f * ax);
    float r = (1.f - e) / (1.f + e);
    return copysignf(r, x);
}

// resident-B MFMA: B pinned in AGPR via "a" constraint
#define MFMA_AG(c, aa, bb) \
    asm volatile("v_mfma_f32_16x16x32_f16 %0, %1, %2, %0" : "+v"(c) : "v"(aa), "a"(bb))
// streamed B (L2 or LDS) in VGPR
#define MFMA_VG(c, aa, bb) \
    asm volatile("v_mfma_f32_16x16x32_f16 %0, %1, %2, %0" : "+v"(c) : "v"(aa), "v"(bb))

// ---------------- prep: concat QCNN weights into one buffer ----------------
__global__ void concat_qw(const float* __restrict__ fm_w, const float* __restrict__ fm_b,
                          const float* __restrict__ c1_w, const float* __restrict__ c1_b,
                          const float* __restrict__ p1_w, const float* __restrict__ p1_b,
                          const float* __restrict__ c2_w, const float* __restrict__ c2_b,
                          const float* __restrict__ p2_w, const float* __restrict__ p2_b,
                          const float* __restrict__ c3_w, const float* __restrict__ c3_b,
                          float* __restrict__ qw) {
    for (int k = threadIdx.x; k < 780; k += 256) {
        float v;
        if      (k < 128) v = fm_w[k];
        else if (k < 144) v = fm_b[k-128];
        else if (k < 400) v = c1_w[k-144];
        else if (k < 416) v = c1_b[k-400];
        else if (k < 608) v = p1_w[k-416];
        else if (k < 620) v = p1_b[k-608];
        else if (k < 716) v = c2_w[k-620];
        else if (k < 724) v = c2_b[k-716];
        else if (k < 756) v = p2_w[k-724];
        else if (k < 760) v = p2_b[k-756];
        else if (k < 776) v = c3_w[k-760];
        else              v = c3_b[k-776];
        qw[k] = v;
    }
}

// ---------------- prep: pack LSTM h-weights as MFMA B-fragments (f16) ----------------
// B-frag for mfma_f32_16x16x32_f16: lane l holds col l&15, k = (l>>4)*8 + e.
// k-element-order errors cancel between A and B. bfragsG[((n*8+q)*64+l)].
__global__ void pack_bfrag(const float* __restrict__ f_w, const float* __restrict__ i_w,
                           const float* __restrict__ u_w, const float* __restrict__ o_w,
                           uint4* __restrict__ bfragsG) {
    int idx = blockIdx.x * 256 + threadIdx.x;      // 0..32767
    int l = idx & 63, q = (idx >> 6) & 7, n = idx >> 9;
    int col = n * 16 + (l & 15);
    int g = col >> 8, j = col & 255;
    const float* W = (g == 0) ? f_w : (g == 1) ? i_w : (g == 2) ? u_w : o_w;
    union { uint4 u; _Float16 h[8]; } P;
#pragma unroll
    for (int e = 0; e < 8; ++e) {
        int k = q * 32 + ((l >> 4) * 8) + e;       // 0..255 (h part only)
        P.h[e] = (_Float16)W[j * 260 + 4 + k];
    }
    bfragsG[idx] = P.u;
}

// ---------------- prep: pack x-part weights xwG[g][k][j] f16 ----------------
__global__ void pack_xw(const float* __restrict__ f_w, const float* __restrict__ i_w,
                        const float* __restrict__ u_w, const float* __restrict__ o_w,
                        _Float16* __restrict__ xwG) {
    int t = blockIdx.x * 256 + threadIdx.x;        // 0..4095
    int g = t >> 10, k = (t >> 8) & 3, j = t & 255;
    const float* W = (g == 0) ? f_w : (g == 1) ? i_w : (g == 2) ? u_w : o_w;
    xwG[t] = (_Float16)W[j * 260 + k];
}

// ---------------- QCNN feature extractor ----------------
__global__ void qcnn_kernel(const float* __restrict__ in, const float* __restrict__ qw,
                            _Float16* __restrict__ feats) {
    int r = blockIdx.x * 256 + threadIdx.x;   // 0..131071
    const float* x = in + (size_t)r * 8;
    float v0[8];
#pragma unroll
    for (int i = 0; i < 8; ++i) v0[i] = x[i];
    float v1[16];
#pragma unroll
    for (int o = 0; o < 16; ++o) {
        float s = qw[128 + o];
#pragma unroll
        for (int i = 0; i < 8; ++i) s += qw[o*8 + i] * v0[i];
        v1[o] = tanhf_(s);
    }
    float v2[16];
#pragma unroll
    for (int o = 0; o < 16; ++o) {
        float s = qw[400 + o];
#pragma unroll
        for (int i = 0; i < 16; ++i) s += qw[144 + o*16 + i] * v1[i];
        v2[o] = tanhf_(s);
    }
    float v3[12];
#pragma unroll
    for (int o = 0; o < 12; ++o) {
        float s = qw[608 + o];
#pragma unroll
        for (int i = 0; i < 16; ++i) s += qw[416 + o*16 + i] * v2[i];
        v3[o] = tanhf_(s);
    }
    float v4[8];
#pragma unroll
    for (int o = 0; o < 8; ++o) {
        float s = qw[716 + o];
#pragma unroll
        for (int i = 0; i < 12; ++i) s += qw[620 + o*12 + i] * v3[i];
        v4[o] = tanhf_(s);
    }
    float v5[4];
#pragma unroll
    for (int o = 0; o < 4; ++o) {
        float s = qw[756 + o];
#pragma unroll
        for (int i = 0; i < 8; ++i) s += qw[724 + o*8 + i] * v4[i];
        v5[o] = tanhf_(s);
    }
    union { uint32_t u[2]; _Float16 h[4]; } P;
#pragma unroll
    for (int o = 0; o < 4; ++o) {
        float s = qw[776 + o];
#pragma unroll
        for (int i = 0; i < 4; ++i) s += qw[760 + o*4 + i] * v5[i];
        P.h[o] = (_Float16)tanhf_(s);
    }
    *reinterpret_cast<uint2*>(feats + (size_t)r * 4) = make_uint2(P.u[0], P.u[1]);
}

// ---------------- persistent MFMA LSTM: 256 blocks x 256 threads ----------------
// Round-6 failure audit: demanded 368 AGPR + 252 VGPR = 620 > 512 unified regs
// -> compiler reloaded B from L2 + accvgpr_write per use (VALUBusy 31% == the
// copy traffic; L2 at 33 TB/s ceiling). Fix: resident = 72 frags = 288 AGPR
// (q0..3 all 16 tiles + q4 for tiles of gate-blocks 0,1); LDS q6,q7 (+q5 of
// block 3); remaining 20 frags/wave STREAMED from L2 each step (8 TB/s, well
// under the 34 TB/s ceiling), issued at block top, covered by >=16 AGPR MFMAs.
// MFMA accumulation strictly ascending q0->q7 == round-5 order (absmax 9.8e-4).
__global__ __launch_bounds__(256, 1)
void lstm_kernel(const uint4* __restrict__ bfragsG, const _Float16* __restrict__ xwG,
                 const _Float16* __restrict__ feats,
                 const float* __restrict__ f_b, const float* __restrict__ i_b,
                 const float* __restrict__ u_b, const float* __restrict__ o_b,
                 const float* __restrict__ head_w, const float* __restrict__ head_bp,
                 float* __restrict__ out) {
    __shared__ uint4     bldsQ67[2][64][64];         // 131072 B : B q=6,7 all tiles
    __shared__ uint4     bldsQ5o[16][64];            //  16384 B : B q=5, tiles 48..63
    __shared__ float     stripL[4][4][64][2];        //   8192 B : [wave][g][jl][sample]
    __shared__ __align__(16) _Float16 combL[2][2][256]; // 2048 B : [buf][sample][k]
    __shared__ float     redL[2][2][4];              //     64 B

    const int tid = threadIdx.x;
    const int w   = tid >> 6;          // wave 0..3
    const int l   = tid & 63;          // lane
    const int s0  = blockIdx.x * 2;
    const int j   = w * 64 + l;        // epilogue output dim

    // ---- init LDS ----
    for (int i = tid; i < 8192; i += 256) {
        int n = i >> 7, qq = (i >> 6) & 1, ll = i & 63;
        bldsQ67[qq][n][ll] = bfragsG[(n * 8 + 6 + qq) * 64 + ll];
    }
    for (int i = tid; i < 1024; i += 256) {
        int nn = i >> 6, ll = i & 63;
        bldsQ5o[nn][ll] = bfragsG[((48 + nn) * 8 + 5) * 64 + ll];
    }
    reinterpret_cast<uint32_t*>(&combL[0][0][0])[tid] = 0u;   // zero h_0 (buf 0)

    // ---- resident B fragments -> AGPR (288 regs) ----
    // Br03[m][q]: q=0..3, m = gate-block*4 + d (tiles n = (m>>2)*16 + w*4 + (m&3))
    // Br4[m]:    q=4 for m=0..7 (gate-blocks 0,1)
    f16x8 Br03[16][4];
    f16x8 Br4[8];
#pragma unroll
    for (int m = 0; m < 16; ++m) {
        const int n = (m >> 2) * 16 + w * 4 + (m & 3);
#pragma unroll
        for (int q = 0; q < 4; ++q) {
            Br03[m][q] = *reinterpret_cast<const f16x8*>(bfragsG + (n * 8 + q) * 64 + l);
            asm volatile("" : "+a"(Br03[m][q]));
        }
    }
#pragma unroll
    for (int m = 0; m < 8; ++m) {
        const int n = (m >> 2) * 16 + w * 4 + (m & 3);
        Br4[m] = *reinterpret_cast<const f16x8*>(bfragsG + (n * 8 + 4) * 64 + l);
        asm volatile("" : "+a"(Br4[m]));
    }

    float bias_[4] = { f_b[j], i_b[j], u_b[j], o_b[j] };
    const float hwj = head_w[j];
    const float hb  = head_bp[0];
    uint32_t xw01[4], xw23[4];
#pragma unroll
    for (int g = 0; g < 4; ++g) {
        union { uint32_t u; _Float16 h[2]; } P;
        P.h[0] = xwG[g*1024 +       j]; P.h[1] = xwG[g*1024 + 256 + j];
        xw01[g] = P.u;
        P.h[0] = xwG[g*1024 + 512 + j]; P.h[1] = xwG[g*1024 + 768 + j];
        xw23[g] = P.u;
    }
    uint2 xr0 = *reinterpret_cast<const uint2*>(feats + ((size_t)0 * BATCH + s0    ) * 4);
    uint2 xr1 = *reinterpret_cast<const uint2*>(feats + ((size_t)0 * BATCH + s0 + 1) * 4);

    __syncthreads();

    float cs0 = 0.f, cs1 = 0.f;        // c-state for (j, sample 0/1)

#pragma unroll 1
    for (int t = 0; t < T_STEPS; ++t) {
        uint2 xn0 = xr0, xn1 = xr1;
        if (t + 1 < T_STEPS) {
            xn0 = *reinterpret_cast<const uint2*>(feats + ((size_t)(t+1) * BATCH + s0    ) * 4);
            xn1 = *reinterpret_cast<const uint2*>(feats + ((size_t)(t+1) * BATCH + s0 + 1) * 4);
        }

        // ---- A fragments for this step (8 x ds_read_b128, broadcast-heavy) ----
        const _Float16* abase = &combL[t & 1][l & 1][(l >> 4) * 8];
        f16x8 A_[8];
#pragma unroll
        for (int q = 0; q < 8; ++q)
            A_[q] = *reinterpret_cast<const f16x8*>(abase + q * 32);

        // ---- 4 gate blocks: tiles m = 4b..4b+3, ascending q accumulation ----
#pragma unroll
        for (int b = 0; b < 4; ++b) {
            // L2-streamed frags for THIS block (issued first; consumed at q4/q5,
            // >=16 AGPR MFMAs (~270 cy) later -> L2 latency covered)
            f16x8 sm[8];
#pragma unroll
            for (int d = 0; d < 4; ++d) {
                const int n = b * 16 + w * 4 + d;
                if (b <= 1)      sm[d] = *reinterpret_cast<const f16x8*>(bfragsG + (n * 8 + 5) * 64 + l);
                else             sm[d] = *reinterpret_cast<const f16x8*>(bfragsG + (n * 8 + 4) * 64 + l);
            }
            if (b == 2) {
#pragma unroll
                for (int d = 0; d < 4; ++d) {
                    const int n = 2 * 16 + w * 4 + d;
                    sm[4 + d] = *reinterpret_cast<const f16x8*>(bfragsG + (n * 8 + 5) * 64 + l);
                }
            }
            // LDS frags
            f16x8 t6[4], t7[4], t5[4];
#pragma unroll
            for (int d = 0; d < 4; ++d) {
                const int n = b * 16 + w * 4 + d;
                t6[d] = *reinterpret_cast<const f16x8*>(&bldsQ67[0][n][l]);
                t7[d] = *reinterpret_cast<const f16x8*>(&bldsQ67[1][n][l]);
            }
            if (b == 3) {
#pragma unroll
                for (int d = 0; d < 4; ++d)
                    t5[d] = *reinterpret_cast<const f16x8*>(&bldsQ5o[w * 4 + d][l]);
            }

            f32x4 c0 = {0.f,0.f,0.f,0.f}, c1 = {0.f,0.f,0.f,0.f};
            f32x4 c2 = {0.f,0.f,0.f,0.f}, c3 = {0.f,0.f,0.f,0.f};
            asm volatile("s_nop 1" : "+v"(c0), "+v"(c1), "+v"(c2), "+v"(c3));

            // q = 0..3 (AGPR-resident)
#pragma unroll
            for (int q = 0; q < 4; ++q) {
                MFMA_AG(c0, A_[q], Br03[4*b+0][q]); MFMA_AG(c1, A_[q], Br03[4*b+1][q]);
                MFMA_AG(c2, A_[q], Br03[4*b+2][q]); MFMA_AG(c3, A_[q], Br03[4*b+3][q]);
            }
            // q = 4
            if (b <= 1) {
                MFMA_AG(c0, A_[4], Br4[4*b+0]); MFMA_AG(c1, A_[4], Br4[4*b+1]);
                MFMA_AG(c2, A_[4], Br4[4*b+2]); MFMA_AG(c3, A_[4], Br4[4*b+3]);
            } else {
                MFMA_VG(c0, A_[4], sm[0]); MFMA_VG(c1, A_[4], sm[1]);
                MFMA_VG(c2, A_[4], sm[2]); MFMA_VG(c3, A_[4], sm[3]);
            }
            // q = 5
            if (b <= 1) {
                MFMA_VG(c0, A_[5], sm[0]); MFMA_VG(c1, A_[5], sm[1]);
                MFMA_VG(c2, A_[5], sm[2]); MFMA_VG(c3, A_[5], sm[3]);
            } else if (b == 2) {
                MFMA_VG(c0, A_[5], sm[4]); MFMA_VG(c1, A_[5], sm[5]);
                MFMA_VG(c2, A_[5], sm[6]); MFMA_VG(c3, A_[5], sm[7]);
            } else {
                MFMA_VG(c0, A_[5], t5[0]); MFMA_VG(c1, A_[5], t5[1]);
                MFMA_VG(c2, A_[5], t5[2]); MFMA_VG(c3, A_[5], t5[3]);
            }
            // q = 6, 7 (LDS)
            MFMA_VG(c0, A_[6], t6[0]); MFMA_VG(c1, A_[6], t6[1]);
            MFMA_VG(c2, A_[6], t6[2]); MFMA_VG(c3, A_[6], t6[3]);
            MFMA_VG(c0, A_[7], t7[0]); MFMA_VG(c1, A_[7], t7[1]);
            MFMA_VG(c2, A_[7], t7[2]); MFMA_VG(c3, A_[7], t7[3]);

            // MFMA(D in VGPR) -> VALU read hazard spacing
            asm volatile("s_nop 7\n\ts_nop 7" : "+v"(c0), "+v"(c1), "+v"(c2), "+v"(c3));

            if (l < 16) {   // rows 0,1 = samples 0,1 (C layout: col=lane&15, row=reg)
                *reinterpret_cast<float2*>(&stripL[w][b][0*16 + l][0]) = make_float2(c0[0], c0[1]);
                *reinterpret_cast<float2*>(&stripL[w][b][1*16 + l][0]) = make_float2(c1[0], c1[1]);
                *reinterpret_cast<float2*>(&stripL[w][b][2*16 + l][0]) = make_float2(c2[0], c2[1]);
                *reinterpret_cast<float2*>(&stripL[w][b][3*16 + l][0]) = make_float2(c3[0], c3[1]);
            }
        }

        // same-wave producer/consumer: drain LDS writes
        asm volatile("s_waitcnt lgkmcnt(0)" ::: "memory");
        __builtin_amdgcn_wave_barrier();

        // ---- all-lane epilogue: lane handles (j, s=0) and (j, s=1) ----
        float pre0[4], pre1[4];
#pragma unroll
        for (int g = 0; g < 4; ++g) {
            float2 gv = *reinterpret_cast<const float2*>(&stripL[w][g][l][0]);
            pre0[g] = fdot2(xw01[g], xr0.x, fdot2(xw23[g], xr0.y, gv.x + bias_[g]));
            pre1[g] = fdot2(xw01[g], xr1.x, fdot2(xw23[g], xr1.y, gv.y + bias_[g]));
        }
        const float fg0 = sigmoidf_(pre0[0]), fg1 = sigmoidf_(pre1[0]);
        const float ig0 = sigmoidf_(pre0[1]), ig1 = sigmoidf_(pre1[1]);
        const float ug0 = tanhf_(pre0[2]),    ug1 = tanhf_(pre1[2]);
        const float og0 = sigmoidf_(pre0[3]), og1 = sigmoidf_(pre1[3]);
        cs0 = fg0 * cs0 + ig0 * ug0;
        cs1 = fg1 * cs1 + ig1 * ug1;
        const float h0 = og0 * tanhf_(cs0);
        const float h1 = og1 * tanhf_(cs1);

        _Float16* nb = &combL[(t + 1) & 1][0][0];
        nb[j]       = (_Float16)h0;
        nb[256 + j] = (_Float16)h1;

        float p0 = h0 * hwj, p1 = h1 * hwj;
#pragma unroll
        for (int off = 32; off; off >>= 1) {
            p0 += __shfl_down(p0, off);
            p1 += __shfl_down(p1, off);
        }
        if (l == 0) { redL[t & 1][0][w] = p0; redL[t & 1][1][w] = p1; }

        xr0 = xn0; xr1 = xn1;
        __syncthreads();                       // the ONE barrier per step

        if (tid < 2)
            out[(size_t)t * BATCH + s0 + tid] =
                (redL[t & 1][tid][0] + redL[t & 1][tid][1]) +
                (redL[t & 1][tid][2] + redL[t & 1][tid][3]) + hb;
    }
}

extern "C" void kernel_launch(void* const* d_in, const int* in_sizes, int n_in,
                              void* d_out, int out_size, void* d_ws, size_t ws_size,
                              hipStream_t stream) {
    const float* inputs = (const float*)d_in[0];
    const float* fm_w = (const float*)d_in[1];  const float* fm_b = (const float*)d_in[2];
    const float* c1_w = (const float*)d_in[3];  const float* c1_b = (const float*)d_in[4];
    const float* p1_w = (const float*)d_in[5];  const float* p1_b = (const float*)d_in[6];
    const float* c2_w = (const float*)d_in[7];  const float* c2_b = (const float*)d_in[8];
    const float* p2_w = (const float*)d_in[9];  const float* p2_b = (const float*)d_in[10];
    const float* c3_w = (const float*)d_in[11]; const float* c3_b = (const float*)d_in[12];
    const float* f_w  = (const float*)d_in[13]; const float* f_b  = (const float*)d_in[14];
    const float* i_w  = (const float*)d_in[15]; const float* i_b  = (const float*)d_in[16];
    const float* u_w  = (const float*)d_in[17]; const float* u_b  = (const float*)d_in[18];
    const float* o_w  = (const float*)d_in[19]; const float* o_b  = (const float*)d_in[20];
    const float* head_w = (const float*)d_in[21];
    const float* head_b = (const float*)d_in[22];

    // workspace layout (16B aligned)
    uint4*     bfragsG = (uint4*)d_ws;                                // 524288 B
    _Float16*  xwG     = (_Float16*)((char*)d_ws + 524288);           //   8192 B
    _Float16*  feats   = (_Float16*)((char*)d_ws + 532480);           // 1048576 B
    float*     qw      = (float*)((char*)d_ws + 1581056);             //   3120 B

    hipLaunchKernelGGL(concat_qw, dim3(1), dim3(256), 0, stream,
                       fm_w, fm_b, c1_w, c1_b, p1_w, p1_b, c2_w, c2_b,
                       p2_w, p2_b, c3_w, c3_b, qw);
    hipLaunchKernelGGL(pack_bfrag, dim3(128), dim3(256), 0, stream,
                       f_w, i_w, u_w, o_w, bfragsG);
    hipLaunchKernelGGL(pack_xw, dim3(16), dim3(256), 0, stream,
                       f_w, i_w, u_w, o_w, xwG);
    hipLaunchKernelGGL(qcnn_kernel, dim3(512), dim3(256), 0, stream,
                       inputs, qw, feats);
    hipLaunchKernelGGL(lstm_kernel, dim3(256), dim3(256), 0, stream,
                       bfragsG, xwG, feats,
                       f_b, i_b, u_b, o_b, head_w, head_b, (float*)d_out);
}